// Round 8
// baseline (527.958 us; speedup 1.0000x reference)
//
#include <hip/hip_runtime.h>
#include <cstdint>
#include <cstddef>

// Problem constants: B=64, T=2048, M=512, P=512

typedef float  floatx4 __attribute__((ext_vector_type(4)));
typedef short  shortx8 __attribute__((ext_vector_type(8)));
typedef unsigned int uintx4 __attribute__((ext_vector_type(4)));

__device__ __forceinline__ short f2bf_rne(float f) {
  unsigned u = __float_as_uint(f);
  unsigned r = u + 0x7FFFu + ((u >> 16) & 1u);
  return (short)(r >> 16);
}

// pack two fp32 -> two bf16 (truncation) in one v_perm_b32
__device__ __forceinline__ unsigned pack_bf_trunc(float lo, float hi) {
  return __builtin_amdgcn_perm(__float_as_uint(hi), __float_as_uint(lo), 0x07060302u);
}

#define GLOAD_LDS16(gptr, lptr)                                                 \
  __builtin_amdgcn_global_load_lds(                                             \
      (const __attribute__((address_space(1))) void*)(gptr),                    \
      (__attribute__((address_space(3))) void*)(lptr), 16, 0, 0)

#define SB() __builtin_amdgcn_sched_barrier(0)
#define WAIT_VM0() asm volatile("s_waitcnt vmcnt(0)" ::: "memory")
#define WAIT_VM4() asm volatile("s_waitcnt vmcnt(4)" ::: "memory")
#define WAIT_VM8() asm volatile("s_waitcnt vmcnt(8)" ::: "memory")
#define WAIT_LGKM0() asm volatile("s_waitcnt lgkmcnt(0)" ::: "memory")
#define BAR() __builtin_amdgcn_s_barrier()

// ---------------------------------------------------------------------------
// Kernel 1: prep.
//   blocks 0..127:   S[b][n] = ds@W_d + b_wd + b_ud  (fp32), 4-way ILP
//   blocks 128..383: UT = pre-swizzled bf16 LDS byte-image of U_d^T for BK=64:
//                    16 tiles (cb*8+kt) of 16384 shorts: [n 0..255][8 granules
//                    of 16B]; physical granule gp holds logical gl = gp^(n&7),
//                    i.e. k = kt*64 + gl*8 + 0..7, col = cb*256+n.
//   blocks 384..511: zero d_out (logit accumulator)
// ---------------------------------------------------------------------------
extern "C" __global__ __launch_bounds__(256) void prep_kernel(
    const float* __restrict__ hidden, const float* __restrict__ cell,
    const float* __restrict__ W_d, const float* __restrict__ b_wd,
    const float* __restrict__ U_d, const float* __restrict__ b_ud,
    float* __restrict__ S, short* __restrict__ UT, float* __restrict__ lzero)
{
  int bx = blockIdx.x, tid = threadIdx.x;
  if (bx < 128) {
    int idx = bx * 256 + tid;          // 0..32767
    int b = idx >> 9, n = idx & 511;
    const float* h = hidden + b * 512;
    const float* c = cell   + b * 512;
    float a0 = b_wd[n] + b_ud[n], a1 = 0.f, a2 = 0.f, a3 = 0.f;
    for (int k = 0; k < 512; k += 4) {
      a0 = fmaf(h[k + 0], W_d[(k + 0) * 512 + n], a0);
      a1 = fmaf(h[k + 1], W_d[(k + 1) * 512 + n], a1);
      a2 = fmaf(h[k + 2], W_d[(k + 2) * 512 + n], a2);
      a3 = fmaf(h[k + 3], W_d[(k + 3) * 512 + n], a3);
    }
    for (int k = 0; k < 512; k += 4) {
      a0 = fmaf(c[k + 0], W_d[(k + 512) * 512 + n], a0);
      a1 = fmaf(c[k + 1], W_d[(k + 513) * 512 + n], a1);
      a2 = fmaf(c[k + 2], W_d[(k + 514) * 512 + n], a2);
      a3 = fmaf(c[k + 3], W_d[(k + 515) * 512 + n], a3);
    }
    S[idx] = (a0 + a1) + (a2 + a3);
  } else if (bx < 384) {
    int idx  = (bx - 128) * 1024 + tid * 4;  // short index into UT image
    int tile = idx >> 14;                    // 0..15 = cb*8 + kt
    int cb = tile >> 3, kt = tile & 7;
    int sI = idx & 16383;
    int n  = sI >> 6;                        // 0..255
    int gp = (sI >> 3) & 7;                  // physical 16B granule
    int bb = sI & 7;                         // 0 or 4
    int gl = gp ^ (n & 7);                   // logical granule
    int k0 = kt * 64 + gl * 8 + bb;
    int ng = cb * 256 + n;
    unsigned lo = (unsigned short)f2bf_rne(U_d[(size_t)(k0 + 0) * 512 + ng]) |
                  ((unsigned)(unsigned short)f2bf_rne(U_d[(size_t)(k0 + 1) * 512 + ng]) << 16);
    unsigned hi = (unsigned short)f2bf_rne(U_d[(size_t)(k0 + 2) * 512 + ng]) |
                  ((unsigned)(unsigned short)f2bf_rne(U_d[(size_t)(k0 + 3) * 512 + ng]) << 16);
    uint2 w; w.x = lo; w.y = hi;
    *(uint2*)(UT + idx) = w;
  } else {
    int idx = ((bx - 384) * 256 + tid) * 4;
    floatx4 z = {0.f, 0.f, 0.f, 0.f};
    *(floatx4*)(lzero + idx) = z;
  }
}

// ---------------------------------------------------------------------------
// Kernel 2: fused GEMM + tanh + dot(v) -> atomicAdd partial logits.
// 128x256 tile / block, 8 waves (2Mx4N, each 64x64), BK=64, 1 barrier/K-tile.
// A: fp32 global -> regs (2-deep dbuf, full-iteration prefetch) -> bf16 ->
//    swizzled LDS.  Parity invariant: A(T+1) lives in areg[(T+1)&1]; iter T
//    issues A(T+2) into areg[T&1] (same buffer parity, consumed next iter).
// B: pre-swizzled UT image -> linear global_load_lds (L2-resident).
// LDS 96 KB (A 2x16 KB, B 2x32 KB) -> 1 block/CU, 2 waves/SIMD.
// Counted vmcnt: VM8/VM4 mid-loop, VM0 only at the last prefetch (T==6).
// ---------------------------------------------------------------------------
struct GemmState {
  short (*As)[8192];                 // [2][128 rows][64 k] bf16 swizzled
  short (*Bs)[16384];                // [2][256 n   ][64 k] bf16 swizzled
  const float* aptr;
  const short* bsrc;
  int bldsbase;
  int afrag0, bfrag0, awbase;
};

__device__ __forceinline__ void a_pack_write(short* An, int awbase,
                                             const floatx4* ar) {
  uintx4 w0, w1;
  w0.x = pack_bf_trunc(ar[0].x, ar[0].y);
  w0.y = pack_bf_trunc(ar[0].z, ar[0].w);
  w0.z = pack_bf_trunc(ar[1].x, ar[1].y);
  w0.w = pack_bf_trunc(ar[1].z, ar[1].w);
  w1.x = pack_bf_trunc(ar[2].x, ar[2].y);
  w1.y = pack_bf_trunc(ar[2].z, ar[2].w);
  w1.z = pack_bf_trunc(ar[3].x, ar[3].y);
  w1.w = pack_bf_trunc(ar[3].z, ar[3].w);
  *(uintx4*)(An + awbase)       = w0;
  *(uintx4*)(An + (awbase ^ 8)) = w1;
}

template <int T>
__device__ __forceinline__ void kiter(
    GemmState& st, floatx4 (&aregA)[4], floatx4 (&aregB)[4],
    floatx4 (&acc)[4][4])
{
  constexpr int CUR = T & 1;
  constexpr int NXT = CUR ^ 1;
  const short* Ab = &st.As[CUR][0];
  const short* Bb = &st.Bs[CUR][0];
  // Parity: A(T+1) is in areg[(T+1)&1]; A(T+2) goes into areg[T&1].
  floatx4* cons = (T & 1) ? aregA : aregB;   // areg[(T+1)&1] : holds A(T+1)
  floatx4* next = (T & 1) ? aregB : aregA;   // areg[T&1]     : gets  A(T+2)
  shortx8 af[4][2], bf[4][2];

  // ---- 1: issue B(T+1) glds -> LDS[NXT]B (prev iter's readers done) ----
  if constexpr (T < 7) {
#pragma unroll
    for (int j = 0; j < 4; ++j)
      GLOAD_LDS16(st.bsrc + (T + 1) * 16384 + j * 512,
                  &st.Bs[NXT][st.bldsbase + j * 512]);
  }
  SB();
  // ---- 1b: issue A(T+2) (full-iteration prefetch distance) ----
  if constexpr (T < 6) {
#pragma unroll
    for (int i = 0; i < 4; ++i)
      next[i] = *(const floatx4*)(st.aptr + (T + 2) * 64 + i * 4);
  }
  SB();
  // ---- 2a: all fragment ds_reads (tile T) ----
#pragma unroll
  for (int tr = 0; tr < 4; ++tr)
#pragma unroll
    for (int s = 0; s < 2; ++s)
      af[tr][s] = *(const shortx8*)(Ab + ((st.afrag0 + tr * 1024) ^ (s * 32)));
#pragma unroll
  for (int tc = 0; tc < 4; ++tc)
#pragma unroll
    for (int s = 0; s < 2; ++s)
      bf[tc][s] = *(const shortx8*)(Bb + ((st.bfrag0 + tc * 1024) ^ (s * 32)));
  SB();
  // ---- 2b: MFMA cluster 1 (tr 0..1) ----
  WAIT_LGKM0(); SB();
  __builtin_amdgcn_s_setprio(1);
#pragma unroll
  for (int tr = 0; tr < 2; ++tr)
#pragma unroll
    for (int tc = 0; tc < 4; ++tc)
#pragma unroll
      for (int s = 0; s < 2; ++s)
        acc[tr][tc] = __builtin_amdgcn_mfma_f32_16x16x32_bf16(
            af[tr][s], bf[tc][s], acc[tr][tc], 0, 0, 0);
  __builtin_amdgcn_s_setprio(0);
  SB();
  // ---- 3+4: A(T+1) landed long ago; pack -> LDS[NXT]A ----
  if constexpr (T < 7) {
    if constexpr (T < 6) { WAIT_VM8(); }  // retire A(T+1)x4; [B(T+1)x4, A(T+2)x4] live
    else                 { WAIT_VM4(); }  // T==6: no A(8); B(7)x4 newer
    SB();
    a_pack_write(&st.As[NXT][0], st.awbase, cons);
    SB();
  }
  // ---- 5: MFMA cluster 2 (tr 2..3); lgkm0 covers my ds_writes ----
  WAIT_LGKM0(); SB();
  __builtin_amdgcn_s_setprio(1);
#pragma unroll
  for (int tr = 2; tr < 4; ++tr)
#pragma unroll
    for (int tc = 0; tc < 4; ++tc)
#pragma unroll
      for (int s = 0; s < 2; ++s)
        acc[tr][tc] = __builtin_amdgcn_mfma_f32_16x16x32_bf16(
            af[tr][s], bf[tc][s], acc[tr][tc], 0, 0, 0);
  __builtin_amdgcn_s_setprio(0);
  SB();
  // ---- 6: counted drain of B(T+1); single barrier ----
  if constexpr (T < 7) {
    if constexpr (T < 6) { WAIT_VM4(); }  // B(T+1) done; A(T+2)x4 in flight
    else                 { WAIT_VM0(); }  // T==6: last prefetch drain
    SB();
    BAR(); SB();
  }
}

extern "C" __global__ __launch_bounds__(512, 2) void attn_gemm(
    const float* __restrict__ A, const short* __restrict__ UT,
    const float* __restrict__ S, const float* __restrict__ vd,
    float* __restrict__ lout)
{
  __shared__ short As[2][8192];      // [buf][128 r][64 k] bf16 swz, 16 KB ea
  __shared__ short Bs[2][16384];     // [buf][256 n][64 k] bf16 swz, 32 KB ea

  const int tid = threadIdx.x;
  const int bx  = blockIdx.x;
  // XCD swizzle: 2048 blocks, 256/XCD; (cb0,cb1) pairs adjacent on one XCD
  // so each A row-panel is HBM-fetched once and L2-shared.
  const int xcd = bx & 7;
  const int wg  = xcd * 256 + (bx >> 3);
  const int cb  = wg & 1;
  const int rb  = wg >> 1;           // 0..1023
  const int row0 = rb << 7;
  const int col0 = cb << 8;
  const int wave = tid >> 6;
  const int lane = tid & 63;
  const int wr = wave >> 2, wc = wave & 3;   // 2M x 4N; per-wave 64x64
  const int q = lane >> 4, l15 = lane & 15;

  GemmState st;
  st.As = As;
  st.Bs = Bs;

  // A staging: thread owns row tid>>2, k-quarter tid&3 (4 float4 / K-tile)
  const int arow = tid >> 2;
  const int akq  = tid & 3;
  st.aptr   = A + (size_t)(row0 + arow) * 512 + akq * 16;
  st.awbase = arow * 64 + (((akq * 2) ^ (arow & 7)) << 3);

  // B staging: 4 glds shots of 1 KB per wave per K-tile (32 KB total)
  st.bsrc     = UT + (size_t)cb * 131072 + wave * 2048 + lane * 8;
  st.bldsbase = wave * 2048;

  // fragment read bases (swizzled; row&7 == l15&7 everywhere)
  const int fgp = (q ^ (l15 & 7)) << 3;
  st.afrag0 = (wr * 64 + l15) * 64 + fgp;   // + tr*1024, ^(s*32)
  st.bfrag0 = (wc * 64 + l15) * 64 + fgp;   // + tc*1024, ^(s*32)

  floatx4 acc[4][4];
#pragma unroll
  for (int i = 0; i < 4; ++i)
#pragma unroll
    for (int j = 0; j < 4; ++j)
      acc[i][j] = (floatx4){0.f, 0.f, 0.f, 0.f};

  floatx4 aregA[4], aregB[4];

  // ------------------- prologue -------------------
  SB();
#pragma unroll
  for (int i = 0; i < 4; ++i) aregA[i] = *(const floatx4*)(st.aptr + i * 4); // A(0)
  SB();
#pragma unroll
  for (int j = 0; j < 4; ++j)
    GLOAD_LDS16(st.bsrc + j * 512, &Bs[0][st.bldsbase + j * 512]);           // B(0)
  SB();
  WAIT_VM4(); SB();                  // A(0) done (issued first); B(0) in flight
  a_pack_write(&As[0][0], st.awbase, aregA);
  SB();
  // A(1) -> aregB = areg[1&1]: establishes the parity invariant for kiter<0>
#pragma unroll
  for (int i = 0; i < 4; ++i) aregB[i] = *(const floatx4*)(st.aptr + 64 + i * 4); // A(1)
  SB();
  WAIT_VM4(); SB();                  // B(0) done; A(1)x4 in flight
  WAIT_LGKM0(); SB();
  BAR(); SB();
  // invariant entering T=0: in flight = A(1)x4 in aregB = areg[(0+1)&1] ✓

  // ------------------- main loop: 8 K-tiles of 64 -------------------
  kiter<0>(st, aregA, aregB, acc);
  kiter<1>(st, aregA, aregB, acc);
  kiter<2>(st, aregA, aregB, acc);
  kiter<3>(st, aregA, aregB, acc);
  kiter<4>(st, aregA, aregB, acc);
  kiter<5>(st, aregA, aregB, acc);
  kiter<6>(st, aregA, aregB, acc);
  kiter<7>(st, aregA, aregB, acc);

  // ------------- epilogue: e = tanh(acc + S[b][n]); dot with v; atomics -----
  const int bb = rb >> 4;            // 128 rows/block, 2048 rows/batch
  const float* Srow = S + bb * 512;
  float sv[4], vv[4];
#pragma unroll
  for (int tc = 0; tc < 4; ++tc) {
    int n = col0 + wc * 64 + tc * 16 + l15;
    sv[tc] = Srow[n];
    vv[tc] = vd[n];
  }
#pragma unroll
  for (int tr = 0; tr < 4; ++tr) {
#pragma unroll
    for (int r = 0; r < 4; ++r) {
      float ssum = 0.f;
#pragma unroll
      for (int tc = 0; tc < 4; ++tc) {
        float x = acc[tr][tc][r] + sv[tc];
        x = fminf(15.f, fmaxf(-15.f, x));
        float e2 = __expf(2.f * x);
        float e = (e2 - 1.f) / (e2 + 1.f);  // tanh
        ssum += e * vv[tc];
      }
      ssum += __shfl_xor(ssum, 1);
      ssum += __shfl_xor(ssum, 2);
      ssum += __shfl_xor(ssum, 4);
      ssum += __shfl_xor(ssum, 8);
      if (l15 == 0) {
        int row = row0 + wr * 64 + tr * 16 + q * 4 + r;
        atomicAdd(lout + row, ssum);
      }
    }
  }
}

// ---------------------------------------------------------------------------
// Kernel 3: softmax over T=2048, in place on d_out. One block per batch.
// ---------------------------------------------------------------------------
extern "C" __global__ __launch_bounds__(256) void softmax_t(float* __restrict__ l)
{
  int b = blockIdx.x, tid = threadIdx.x;
  int wave = tid >> 6, lane = tid & 63;
  float* row = l + (size_t)b * 2048;
  float v[8];
  float mx = -3.4e38f;
#pragma unroll
  for (int i = 0; i < 8; ++i) { v[i] = row[tid + i * 256]; mx = fmaxf(mx, v[i]); }
#pragma unroll
  for (int m = 1; m < 64; m <<= 1) mx = fmaxf(mx, __shfl_xor(mx, m));
  __shared__ float red[8];
  if (lane == 0) red[wave] = mx;
  __syncthreads();
  mx = fmaxf(fmaxf(red[0], red[1]), fmaxf(red[2], red[3]));
  float s = 0.f;
#pragma unroll
  for (int i = 0; i < 8; ++i) { v[i] = __expf(v[i] - mx); s += v[i]; }
#pragma unroll
  for (int m = 1; m < 64; m <<= 1) s += __shfl_xor(s, m);
  if (lane == 0) red[4 + wave] = s;
  __syncthreads();
  s = red[4] + red[5] + red[6] + red[7];
  float inv = 1.f / s;
#pragma unroll
  for (int i = 0; i < 8; ++i) row[tid + i * 256] = v[i] * inv;
}

// ---------------------------------------------------------------------------
extern "C" void kernel_launch(void* const* d_in, const int* in_sizes, int n_in,
                              void* d_out, int out_size, void* d_ws, size_t ws_size,
                              hipStream_t stream) {
  const float* hidden = (const float*)d_in[0];
  const float* cell   = (const float*)d_in[1];
  const float* enc    = (const float*)d_in[2];
  const float* W_d    = (const float*)d_in[3];
  const float* b_wd   = (const float*)d_in[4];
  const float* U_d    = (const float*)d_in[5];
  const float* b_ud   = (const float*)d_in[6];
  const float* v_d    = (const float*)d_in[7];
  // d_in[8] = b_vd: constant shift over T -> softmax-invariant, unused.
  float* out = (float*)d_out;                     // logits then softmax, in place
  float* S   = (float*)d_ws;                      // 64*512 fp32   = 128 KB
  short* UT  = (short*)((char*)d_ws + 32768 * sizeof(float));  // 512 KB image

  hipLaunchKernelGGL(prep_kernel, dim3(512), dim3(256), 0, stream,
                     hidden, cell, W_d, b_wd, U_d, b_ud, S, UT, out);
  hipLaunchKernelGGL(attn_gemm, dim3(2048), dim3(512), 0, stream,
                     enc, UT, S, v_d, out);
  hipLaunchKernelGGL(softmax_t, dim3(64), dim3(256), 0, stream, out);
}